// Round 2
// baseline (8530.247 us; speedup 1.0000x reference)
//
#include <hip/hip_runtime.h>
#include <stdint.h>

// Problem constants (fixed by the reference)
#define T_STEPS 100
#define Bb 256
#define Hh 1024
#define Dd 1024
#define BM 64
#define BN 64
#define BK 64

typedef _Float16 f16;
typedef _Float16 f16x8 __attribute__((ext_vector_type(8)));
typedef _Float16 f16x4 __attribute__((ext_vector_type(4)));
typedef float    f32x4 __attribute__((ext_vector_type(4)));

// ---------- f32 -> (hi,lo) f16 split: v = hi + lo + O(2^-22 |v|) ----------
__global__ __launch_bounds__(256) void k_f32_split(const float* __restrict__ s,
                                                   f16* __restrict__ hi, f16* __restrict__ lo, int n) {
  int i = (blockIdx.x * blockDim.x + threadIdx.x) * 4;
  if (i >= n) return;
  float4 v = *(const float4*)(s + i);
  f16x4 h = { (f16)v.x, (f16)v.y, (f16)v.z, (f16)v.w };
  f16x4 L = { (f16)(v.x - (float)h.x), (f16)(v.y - (float)h.y),
              (f16)(v.z - (float)h.z), (f16)(v.w - (float)h.w) };
  *(f16x4*)(hi + i) = h;
  *(f16x4*)(lo + i) = L;
}

__global__ __launch_bounds__(256) void k_f32_to_f16(const float* __restrict__ s,
                                                    f16* __restrict__ d, int n) {
  int i = (blockIdx.x * blockDim.x + threadIdx.x) * 4;
  if (i >= n) return;
  float4 v = *(const float4*)(s + i);
  f16x4 o = { (f16)v.x, (f16)v.y, (f16)v.z, (f16)v.w };
  *(f16x4*)(d + i) = o;
}

// ---------- init: hn = LN(0) = ln_bias ----------
__global__ __launch_bounds__(256) void k_init_hn(const float* __restrict__ lnb,
                                                 float* __restrict__ hn0f, float* __restrict__ hn1f,
                                                 f16* __restrict__ h0hi, f16* __restrict__ h0lo,
                                                 f16* __restrict__ h1hi, f16* __restrict__ h1lo) {
  int m = blockIdx.x, tid = threadIdx.x;
  for (int k = 0; k < 4; ++k) {
    int c = tid + k * 256;
    float v = lnb[c];
    f16 h = (f16)v; f16 L = (f16)(v - (float)h);
    size_t idx = (size_t)m * Hh + c;
    hn0f[idx] = v; hn1f[idx] = v;
    h0hi[idx] = h; h0lo[idx] = L;
    h1hi[idx] = h; h1lo[idx] = L;
  }
}

// ---------- GEMM: C[M,N] = A[M,K] @ W[N,K]^T (+bias), K=1024 fixed ----------
// NP=1: single f16 pass. NP=3: split passes (Ah*Bh + Ah*Bl + Al*Bh) summed in
// the same f32 accumulator. 64x64 tile, 4 waves (2x2 of 32x32 via 2x2 16x16x32
// frags), global_load_lds(16B) staging with k-group XOR swizzle (pre-swizzled
// global source + swizzled ds_read; rule #21 both-sides involution).
__device__ __forceinline__ void stage_tile(const f16* __restrict__ g, int r0, int k0,
                                           f16* sdst, int w, int l) {
#pragma unroll
  for (int i = 0; i < 2; ++i) {
    int slot = i * 256 + w * 64 + l;          // 0..511 : 64 rows x 8 chunks of 16B
    int row  = slot >> 3;
    int pkg  = slot & 7;                      // physical 16B chunk in row
    int lg   = pkg ^ (row & 7);               // logical k-group (involution)
    const f16* src = g + (size_t)(r0 + row) * 1024 + k0 + lg * 8;
    f16* dst = sdst + (size_t)(i * 256 + w * 64) * 8;  // wave-uniform base; HW adds lane*16B
    __builtin_amdgcn_global_load_lds((const __attribute__((address_space(1))) void*)src,
                                     (__attribute__((address_space(3))) void*)dst, 16, 0, 0);
  }
}

template <int NP>
__device__ __forceinline__ void gemm_body(const f16* __restrict__ Ah, const f16* __restrict__ Al,
                                          const f16* __restrict__ Bh, const f16* __restrict__ Bl,
                                          float* __restrict__ C, const float* __restrict__ bias,
                                          int N, int m0, int n0) {
  __shared__ alignas(16) f16 sA[2][BM * BK];
  __shared__ alignas(16) f16 sB[2][BN * BK];
  const int tid = threadIdx.x;
  const int w = tid >> 6, l = tid & 63;
  const int wr = w >> 1, wc = w & 1;
  const int lrow = l & 15, lkg = l >> 4;
  const int TOT = NP * 16;

  f32x4 acc[2][2] = {};
  stage_tile(Ah, m0, 0, sA[0], w, l);
  stage_tile(Bh, n0, 0, sB[0], w, l);

  for (int it = 0; it < TOT; ++it) {
    __syncthreads();                          // drains vmcnt -> staged tile visible
    const int cur = it & 1;
    if (it + 1 < TOT) {
      const int nx = it + 1;
      const f16* An = (NP == 3 && nx >= 32) ? Al : Ah;        // pass2 uses A_lo
      const f16* Bn = (NP == 3 && (nx >> 4) == 1) ? Bl : Bh;  // pass1 uses B_lo
      const int k0 = (nx & 15) * BK;
      stage_tile(An, m0, k0, sA[cur ^ 1], w, l);
      stage_tile(Bn, n0, k0, sB[cur ^ 1], w, l);
    }
    const f16* a0 = sA[cur];
    const f16* b0 = sB[cur];
#pragma unroll
    for (int ks = 0; ks < 2; ++ks) {
      f16x8 af[2], bf[2];
#pragma unroll
      for (int fi = 0; fi < 2; ++fi) {
        int row = wr * 32 + fi * 16 + lrow;
        int kg  = ks * 4 + lkg;
        int pkg = kg ^ (row & 7);
        af[fi] = *(const f16x8*)&a0[row * BK + pkg * 8];
      }
#pragma unroll
      for (int fj = 0; fj < 2; ++fj) {
        int row = wc * 32 + fj * 16 + lrow;   // B-tile row = output column
        int kg  = ks * 4 + lkg;
        int pkg = kg ^ (row & 7);
        bf[fj] = *(const f16x8*)&b0[row * BK + pkg * 8];
      }
#pragma unroll
      for (int fi = 0; fi < 2; ++fi)
#pragma unroll
        for (int fj = 0; fj < 2; ++fj)
          acc[fi][fj] = __builtin_amdgcn_mfma_f32_16x16x32_f16(af[fi], bf[fj], acc[fi][fj], 0, 0, 0);
    }
  }
  // C/D layout: col = lane&15, row = (lane>>4)*4 + r  [m89, dtype-independent]
#pragma unroll
  for (int fi = 0; fi < 2; ++fi)
#pragma unroll
    for (int fj = 0; fj < 2; ++fj)
#pragma unroll
      for (int r = 0; r < 4; ++r) {
        int row = m0 + wr * 32 + fi * 16 + lkg * 4 + r;
        int col = n0 + wc * 32 + fj * 16 + lrow;
        float v = acc[fi][fj][r];
        if (bias) v += bias[col];
        C[(size_t)row * N + col] = v;
      }
}

__global__ __launch_bounds__(256) void k_gemm1(const f16* __restrict__ A, const f16* __restrict__ B,
                                               float* __restrict__ C, const float* __restrict__ bias,
                                               int N) {
  gemm_body<1>(A, nullptr, B, nullptr, C, bias, N, blockIdx.x * BM, blockIdx.y * BN);
}

__global__ __launch_bounds__(256) void k_gemm3(const f16* __restrict__ Ah, const f16* __restrict__ Al,
                                               const f16* __restrict__ Bh, const f16* __restrict__ Bl,
                                               float* __restrict__ C, const float* __restrict__ bias,
                                               int N) {
  gemm_body<3>(Ah, Al, Bh, Bl, C, bias, N, blockIdx.x * BM, blockIdx.y * BN);
}

// gi and gh for one GRU layer in one launch (blockIdx.z selects), split precision
__global__ __launch_bounds__(256) void k_gemm_dual3(
    const f16* __restrict__ A0h, const f16* __restrict__ A0l,
    const f16* __restrict__ B0h, const f16* __restrict__ B0l, float* __restrict__ C0,
    const f16* __restrict__ A1h, const f16* __restrict__ A1l,
    const f16* __restrict__ B1h, const f16* __restrict__ B1l, float* __restrict__ C1, int N) {
  const f16* Ah = blockIdx.z ? A1h : A0h;
  const f16* Al = blockIdx.z ? A1l : A0l;
  const f16* Bh = blockIdx.z ? B1h : B0h;
  const f16* Bl = blockIdx.z ? B1l : B0l;
  float*     C  = blockIdx.z ? C1  : C0;
  gemm_body<3>(Ah, Al, Bh, Bl, C, nullptr, N, blockIdx.x * BM, blockIdx.y * BN);
}

// ---------- block-wide sum of 2 values (256 threads) ----------
__device__ __forceinline__ void block_sum2(float& a, float& b) {
#pragma unroll
  for (int o = 32; o > 0; o >>= 1) { a += __shfl_down(a, o, 64); b += __shfl_down(b, o, 64); }
  __shared__ float sa[4], sb[4];
  int w = threadIdx.x >> 6, l = threadIdx.x & 63;
  if (l == 0) { sa[w] = a; sb[w] = b; }
  __syncthreads();
  a = sa[0] + sa[1] + sa[2] + sa[3];
  b = sb[0] + sb[1] + sb[2] + sb[3];
}

__device__ __forceinline__ void split_store(float v, f16* hi, f16* lo, size_t idx) {
  f16 h = (f16)v;
  hi[idx] = h;
  lo[idx] = (f16)(v - (float)h);
}

// ---------- GRU gate + LN fused. One block per batch row. ----------
// Reference quirk: the gh GEMM input AND the z*h term both use hn = LN(h_prev);
// raw h never persists. State carried: hnf (f32) + hn hi/lo (GEMM input).
__global__ __launch_bounds__(256) void k_gru_gate(const float* __restrict__ gi, const float* __restrict__ gh,
                                                  float* __restrict__ hnf,
                                                  f16* __restrict__ hnhi, f16* __restrict__ hnlo,
                                                  f16* __restrict__ xhi, f16* __restrict__ xlo,
                                                  const float* __restrict__ bih, const float* __restrict__ bhh,
                                                  const float* __restrict__ lng, const float* __restrict__ lnb,
                                                  f16* __restrict__ outp, long ostride) {
  int m = blockIdx.x, tid = threadIdx.x;
  float h[4];
  float s1 = 0.f, s2 = 0.f;
#pragma unroll
  for (int k = 0; k < 4; ++k) {
    int c = tid + k * 256;
    size_t g0 = (size_t)m * (3 * Hh) + c;
    float rr  = (gi[g0]          + bih[c])          + (gh[g0]          + bhh[c]);
    float zz  = (gi[g0 + Hh]     + bih[Hh + c])     + (gh[g0 + Hh]     + bhh[Hh + c]);
    float in_ =  gi[g0 + 2 * Hh] + bih[2 * Hh + c];
    float hn_ =  gh[g0 + 2 * Hh] + bhh[2 * Hh + c];
    float r = 1.f / (1.f + expf(-rr));
    float z = 1.f / (1.f + expf(-zz));
    float n = tanhf(in_ + r * hn_);
    float hp = hnf[(size_t)m * Hh + c];          // LN'd previous hidden (f32)
    float hv = (1.f - z) * n + z * hp;
    h[k] = hv;
    split_store(hv, xhi, xlo, (size_t)m * Hh + c);      // next-GEMM input (split)
    if (outp) outp[(size_t)m * ostride + c] = (f16)hv;  // outputs[b*T+t] (single)
    s1 += hv; s2 += hv * hv;
  }
  block_sum2(s1, s2);
  float mean = s1 * (1.f / Hh);
  float var  = s2 * (1.f / Hh) - mean * mean;
  float rs   = rsqrtf(var + 1e-5f);
#pragma unroll
  for (int k = 0; k < 4; ++k) {
    int c = tid + k * 256;
    float v = (h[k] - mean) * rs * lng[c] + lnb[c];
    hnf[(size_t)m * Hh + c] = v;
    split_store(v, hnhi, hnlo, (size_t)m * Hh + c);
  }
}

// ---------- LN + ReLU -> f16 (hi or hi+lo) ----------
__global__ __launch_bounds__(256) void k_ln_relu(const float* __restrict__ pre,
                                                 const float* __restrict__ g, const float* __restrict__ b,
                                                 f16* __restrict__ hi, f16* __restrict__ lo) {
  int m = blockIdx.x, tid = threadIdx.x;
  float v[4]; float s1 = 0.f, s2 = 0.f;
#pragma unroll
  for (int k = 0; k < 4; ++k) {
    int c = tid + k * 256;
    float x = pre[(size_t)m * Hh + c];
    v[k] = x; s1 += x; s2 += x * x;
  }
  block_sum2(s1, s2);
  float mean = s1 * (1.f / Hh);
  float var  = s2 * (1.f / Hh) - mean * mean;
  float rs   = rsqrtf(var + 1e-5f);
#pragma unroll
  for (int k = 0; k < 4; ++k) {
    int c = tid + k * 256;
    float y = (v[k] - mean) * rs * g[c] + b[c];
    y = y > 0.f ? y : 0.f;
    f16 hh = (f16)y;
    hi[(size_t)m * Hh + c] = hh;
    if (lo) lo[(size_t)m * Hh + c] = (f16)(y - (float)hh);
  }
}

extern "C" void kernel_launch(void* const* d_in, const int* in_sizes, int n_in,
                              void* d_out, int out_size, void* d_ws, size_t ws_size,
                              hipStream_t stream) {
  (void)in_sizes; (void)n_in; (void)out_size; (void)ws_size;
  const float* x     = (const float*)d_in[0];
  const float* encW1 = (const float*)d_in[1];
  const float* encb1 = (const float*)d_in[2];
  const float* ln1g  = (const float*)d_in[3];
  const float* ln1b  = (const float*)d_in[4];
  const float* encW2 = (const float*)d_in[5];
  const float* encb2 = (const float*)d_in[6];
  const float* ln2g  = (const float*)d_in[7];
  const float* ln2b  = (const float*)d_in[8];
  const float* Wih0  = (const float*)d_in[9];
  const float* Whh0  = (const float*)d_in[10];
  const float* bih0  = (const float*)d_in[11];
  const float* bhh0  = (const float*)d_in[12];
  const float* Wih1  = (const float*)d_in[13];
  const float* Whh1  = (const float*)d_in[14];
  const float* bih1  = (const float*)d_in[15];
  const float* bhh1  = (const float*)d_in[16];
  const float* hng   = (const float*)d_in[17];
  const float* hnb   = (const float*)d_in[18];
  const float* pW1   = (const float*)d_in[19];
  const float* pb1   = (const float*)d_in[20];
  const float* plng  = (const float*)d_in[21];
  const float* plnb  = (const float*)d_in[22];
  const float* pW2   = (const float*)d_in[23];
  const float* pb2   = (const float*)d_in[24];

  // workspace carve-up (~125 MB)
  char* p = (char*)d_ws;
  auto alloc = [&](size_t bytes) { void* r = (void*)p; p += (bytes + 255) & ~(size_t)255; return r; };
  auto fpair = [&](size_t n, f16** hi, f16** lo) {
    *hi = (f16*)alloc(n * 2); *lo = (f16*)alloc(n * 2);
  };
  f16 *We1h, *We1l, *We2h, *We2l, *Wih0h, *Wih0l, *Whh0h, *Whh0l, *Wih1h, *Wih1l, *Whh1h, *Whh1l;
  fpair((size_t)Hh * Dd, &We1h, &We1l);
  fpair((size_t)Hh * Hh, &We2h, &We2l);
  fpair((size_t)3 * Hh * Hh, &Wih0h, &Wih0l);
  fpair((size_t)3 * Hh * Hh, &Whh0h, &Whh0l);
  fpair((size_t)3 * Hh * Hh, &Wih1h, &Wih1l);
  fpair((size_t)3 * Hh * Hh, &Whh1h, &Whh1l);
  f16* pW1h = (f16*)alloc((size_t)Hh * Hh * 2);
  f16* pW2h = (f16*)alloc((size_t)Dd * Hh * 2);
  f16 *xhi, *xlo, *curh, *curl, *x1h, *x1l, *hn0h, *hn0l, *hn1h, *hn1l;
  fpair((size_t)Bb * Dd, &xhi, &xlo);
  fpair((size_t)Bb * Hh, &curh, &curl);   // layer0 input (e, then h1 of prev step)
  fpair((size_t)Bb * Hh, &x1h, &x1l);     // layer1 input (h0 of this step)
  fpair((size_t)Bb * Hh, &hn0h, &hn0l);
  fpair((size_t)Bb * Hh, &hn1h, &hn1l);
  float* hn0f = (float*)alloc((size_t)Bb * Hh * 4);
  float* hn1f = (float*)alloc((size_t)Bb * Hh * 4);
  float* gif  = (float*)alloc((size_t)Bb * 3 * Hh * 4);
  float* ghf  = (float*)alloc((size_t)Bb * 3 * Hh * 4);
  f16* outsh  = (f16*)alloc((size_t)Bb * T_STEPS * Hh * 2);  // [b*T+t, H]
  f16* ph     = outsh;          // proj intermediate aliases outsh (dead by then)
  float* pre  = (float*)d_out;  // d_out doubles as f32 [25600,1024] proj scratch

  auto spl = [&](const float* s, f16* hi, f16* lo, int n) {
    hipLaunchKernelGGL(k_f32_split, dim3((n / 4 + 255) / 256), dim3(256), 0, stream, s, hi, lo, n);
  };
  auto conv = [&](const float* s, f16* d, int n) {
    hipLaunchKernelGGL(k_f32_to_f16, dim3((n / 4 + 255) / 256), dim3(256), 0, stream, s, d, n);
  };
  spl(x, xhi, xlo, Bb * Dd);
  spl(encW1, We1h, We1l, Hh * Dd);
  spl(encW2, We2h, We2l, Hh * Hh);
  spl(Wih0, Wih0h, Wih0l, 3 * Hh * Hh);
  spl(Whh0, Whh0h, Whh0l, 3 * Hh * Hh);
  spl(Wih1, Wih1h, Wih1l, 3 * Hh * Hh);
  spl(Whh1, Whh1h, Whh1l, 3 * Hh * Hh);
  conv(pW1, pW1h, Hh * Hh);
  conv(pW2, pW2h, Dd * Hh);
  hipLaunchKernelGGL(k_init_hn, dim3(Bb), dim3(256), 0, stream, hnb, hn0f, hn1f, hn0h, hn0l, hn1h, hn1l);

  // ---------- encoder (split precision: feeds the amplifying recurrence) ----------
  hipLaunchKernelGGL(k_gemm3, dim3(Bb / BM, Hh / BN), dim3(256), 0, stream,
                     xhi, xlo, We1h, We1l, gif, encb1, Hh);
  hipLaunchKernelGGL(k_ln_relu, dim3(Bb), dim3(256), 0, stream, gif, ln1g, ln1b, x1h, x1l);
  hipLaunchKernelGGL(k_gemm3, dim3(Bb / BM, Hh / BN), dim3(256), 0, stream,
                     x1h, x1l, We2h, We2l, gif, encb2, Hh);
  hipLaunchKernelGGL(k_ln_relu, dim3(Bb), dim3(256), 0, stream, gif, ln2g, ln2b, curh, curl);

  // ---------- GRU: 100 steps x 2 layers, split precision ----------
  for (int t = 0; t < T_STEPS; ++t) {
    hipLaunchKernelGGL(k_gemm_dual3, dim3(Bb / BM, 3 * Hh / BN, 2), dim3(256), 0, stream,
                       curh, curl, Wih0h, Wih0l, gif, hn0h, hn0l, Whh0h, Whh0l, ghf, 3 * Hh);
    hipLaunchKernelGGL(k_gru_gate, dim3(Bb), dim3(256), 0, stream,
                       gif, ghf, hn0f, hn0h, hn0l, x1h, x1l, bih0, bhh0, hng, hnb,
                       (f16*)nullptr, (long)0);
    hipLaunchKernelGGL(k_gemm_dual3, dim3(Bb / BM, 3 * Hh / BN, 2), dim3(256), 0, stream,
                       x1h, x1l, Wih1h, Wih1l, gif, hn1h, hn1l, Whh1h, Whh1l, ghf, 3 * Hh);
    hipLaunchKernelGGL(k_gru_gate, dim3(Bb), dim3(256), 0, stream,
                       gif, ghf, hn1f, hn1h, hn1l, curh, curl, bih1, bhh1, hng, hnb,
                       outsh + (size_t)t * Hh, (long)T_STEPS * Hh);
  }

  // ---------- projection (single f16: outside the recurrence) ----------
  hipLaunchKernelGGL(k_gemm1, dim3(Bb * T_STEPS / BM, Hh / BN), dim3(256), 0, stream,
                     outsh, pW1h, pre, pb1, Hh);
  hipLaunchKernelGGL(k_ln_relu, dim3(Bb * T_STEPS), dim3(256), 0, stream, pre, plng, plnb,
                     ph, (f16*)nullptr);
  hipLaunchKernelGGL(k_gemm1, dim3(Bb * T_STEPS / BM, Dd / BN), dim3(256), 0, stream,
                     ph, pW2h, (float*)d_out, pb2, Dd);
}

// Round 3
// 7342.112 us; speedup vs baseline: 1.1618x; 1.1618x over previous
//
#include <hip/hip_runtime.h>
#include <stdint.h>

// Problem constants (fixed by the reference)
#define T_STEPS 100
#define Bb 256
#define Hh 1024
#define Dd 1024
#define BM 64
#define BN 64
#define BK 64

typedef _Float16 f16;
typedef _Float16 f16x8 __attribute__((ext_vector_type(8)));
typedef _Float16 f16x4 __attribute__((ext_vector_type(4)));
typedef float    f32x4 __attribute__((ext_vector_type(4)));

// ---------- f32 -> (hi,lo) f16 split: v = hi + lo + O(2^-22 |v|) ----------
__global__ __launch_bounds__(256) void k_f32_split(const float* __restrict__ s,
                                                   f16* __restrict__ hi, f16* __restrict__ lo, int n) {
  int i = (blockIdx.x * blockDim.x + threadIdx.x) * 4;
  if (i >= n) return;
  float4 v = *(const float4*)(s + i);
  f16x4 h = { (f16)v.x, (f16)v.y, (f16)v.z, (f16)v.w };
  f16x4 L = { (f16)(v.x - (float)h.x), (f16)(v.y - (float)h.y),
              (f16)(v.z - (float)h.z), (f16)(v.w - (float)h.w) };
  *(f16x4*)(hi + i) = h;
  *(f16x4*)(lo + i) = L;
}

__global__ __launch_bounds__(256) void k_f32_to_f16(const float* __restrict__ s,
                                                    f16* __restrict__ d, int n) {
  int i = (blockIdx.x * blockDim.x + threadIdx.x) * 4;
  if (i >= n) return;
  float4 v = *(const float4*)(s + i);
  f16x4 o = { (f16)v.x, (f16)v.y, (f16)v.z, (f16)v.w };
  *(f16x4*)(d + i) = o;
}

// ---------- init: hn = LN(0) = ln_bias ----------
__global__ __launch_bounds__(256) void k_init_hn(const float* __restrict__ lnb,
                                                 float* __restrict__ hn0f, float* __restrict__ hn1f,
                                                 f16* __restrict__ h0hi, f16* __restrict__ h0lo,
                                                 f16* __restrict__ h1hi, f16* __restrict__ h1lo) {
  int m = blockIdx.x, tid = threadIdx.x;
  for (int k = 0; k < 4; ++k) {
    int c = tid + k * 256;
    float v = lnb[c];
    f16 h = (f16)v; f16 L = (f16)(v - (float)h);
    size_t idx = (size_t)m * Hh + c;
    hn0f[idx] = v; hn1f[idx] = v;
    h0hi[idx] = h; h0lo[idx] = L;
    h1hi[idx] = h; h1lo[idx] = L;
  }
}

// ---------- shared staging helper: NCH 16B-chunks/thread, K stride fixed 1024 ----------
// XOR-swizzle (rule #21): linear LDS dest + inverse-swizzled global source; the
// ds_read applies the same involution. 2-way conflicts only (free, m136).
template <int NCH>
__device__ __forceinline__ void stage_rows(const f16* __restrict__ g, int r0, int k0,
                                           f16* sdst, int tid) {
#pragma unroll
  for (int i = 0; i < NCH; ++i) {
    int slot = i * 256 + tid;
    int row  = slot >> 3;
    int pkg  = slot & 7;
    int lg   = pkg ^ (row & 7);
    const f16* src = g + (size_t)(r0 + row) * 1024 + k0 + lg * 8;
    f16* dst = sdst + (size_t)slot * 8;
    __builtin_amdgcn_global_load_lds((const __attribute__((address_space(1))) void*)src,
                                     (__attribute__((address_space(3))) void*)dst, 16, 0, 0);
  }
}

// ---------- GRU dual GEMM, fused 3-pass split precision ----------
// C[256,3072] = A[256,1024] @ W[3072,1024]^T with A,W in (hi,lo) f16 pairs:
// acc += Ah*Bh + Ah*Bl + Al*Bh, all from one staged K-tile. Tile 64x96, 4 waves
// (2x2), wave-tile 32x48 (2x3 frags of 16x16x32). Grid (4,32,2) = 256 WGs = 1/CU.
// LDS 80 KB. blockIdx.z picks (gi | gh) operand set.
#define FBM 64
#define FBN 96
__global__ __launch_bounds__(256) void k_gru_gemm(
    const f16* __restrict__ A0h, const f16* __restrict__ A0l,
    const f16* __restrict__ B0h, const f16* __restrict__ B0l, float* __restrict__ C0,
    const f16* __restrict__ A1h, const f16* __restrict__ A1l,
    const f16* __restrict__ B1h, const f16* __restrict__ B1l, float* __restrict__ C1) {
  const f16* Ah = blockIdx.z ? A1h : A0h;
  const f16* Al = blockIdx.z ? A1l : A0l;
  const f16* Bh = blockIdx.z ? B1h : B0h;
  const f16* Bl = blockIdx.z ? B1l : B0l;
  float*     C  = blockIdx.z ? C1  : C0;

  __shared__ alignas(16) f16 sAh[2][FBM * BK];
  __shared__ alignas(16) f16 sAl[2][FBM * BK];
  __shared__ alignas(16) f16 sBh[2][FBN * BK];
  __shared__ alignas(16) f16 sBl[2][FBN * BK];

  const int tid = threadIdx.x;
  const int w = tid >> 6, l = tid & 63;
  const int wr = w >> 1, wc = w & 1;
  const int lrow = l & 15, lkg = l >> 4;
  const int m0 = blockIdx.x * FBM, n0 = blockIdx.y * FBN;

  f32x4 acc[2][3] = {};
  stage_rows<2>(Ah, m0, 0, sAh[0], tid);
  stage_rows<2>(Al, m0, 0, sAl[0], tid);
  stage_rows<3>(Bh, n0, 0, sBh[0], tid);
  stage_rows<3>(Bl, n0, 0, sBl[0], tid);

  for (int it = 0; it < 16; ++it) {
    __syncthreads();                       // drains prev stage; protects dbuf reuse
    const int cur = it & 1;
    if (it < 15) {
      const int k0 = (it + 1) * BK;
      stage_rows<2>(Ah, m0, k0, sAh[cur ^ 1], tid);
      stage_rows<2>(Al, m0, k0, sAl[cur ^ 1], tid);
      stage_rows<3>(Bh, n0, k0, sBh[cur ^ 1], tid);
      stage_rows<3>(Bl, n0, k0, sBl[cur ^ 1], tid);
    }
#pragma unroll
    for (int ks = 0; ks < 2; ++ks) {
      f16x8 ah[2], al[2], bh[3], bl[3];
#pragma unroll
      for (int fi = 0; fi < 2; ++fi) {
        int row = wr * 32 + fi * 16 + lrow;
        int pkg = (ks * 4 + lkg) ^ (row & 7);
        ah[fi] = *(const f16x8*)&sAh[cur][row * BK + pkg * 8];
        al[fi] = *(const f16x8*)&sAl[cur][row * BK + pkg * 8];
      }
#pragma unroll
      for (int fj = 0; fj < 3; ++fj) {
        int row = wc * 48 + fj * 16 + lrow;
        int pkg = (ks * 4 + lkg) ^ (row & 7);
        bh[fj] = *(const f16x8*)&sBh[cur][row * BK + pkg * 8];
        bl[fj] = *(const f16x8*)&sBl[cur][row * BK + pkg * 8];
      }
#pragma unroll
      for (int fi = 0; fi < 2; ++fi)
#pragma unroll
        for (int fj = 0; fj < 3; ++fj) {
          acc[fi][fj] = __builtin_amdgcn_mfma_f32_16x16x32_f16(ah[fi], bh[fj], acc[fi][fj], 0, 0, 0);
          acc[fi][fj] = __builtin_amdgcn_mfma_f32_16x16x32_f16(ah[fi], bl[fj], acc[fi][fj], 0, 0, 0);
          acc[fi][fj] = __builtin_amdgcn_mfma_f32_16x16x32_f16(al[fi], bh[fj], acc[fi][fj], 0, 0, 0);
        }
    }
  }
  // C/D layout: col = lane&15, row = (lane>>4)*4 + r  [m89]
#pragma unroll
  for (int fi = 0; fi < 2; ++fi)
#pragma unroll
    for (int fj = 0; fj < 3; ++fj)
#pragma unroll
      for (int r = 0; r < 4; ++r) {
        int row = m0 + wr * 32 + fi * 16 + lkg * 4 + r;
        int col = n0 + wc * 48 + fj * 16 + lrow;
        C[(size_t)row * 3072 + col] = acc[fi][fj][r];
      }
}

// ---------- big single-pass GEMM (projection): 128x128 tile, m97 structure ----------
// wave-tile 64x64 (4x4 frags), 4 waves (2x2). r=2 MFMA:ds_read.
__global__ __launch_bounds__(256) void k_gemm_big(const f16* __restrict__ A, const f16* __restrict__ B,
                                                  float* __restrict__ C, const float* __restrict__ bias,
                                                  int N) {
  __shared__ alignas(16) f16 sA[2][128 * BK];
  __shared__ alignas(16) f16 sB[2][128 * BK];
  const int tid = threadIdx.x;
  const int w = tid >> 6, l = tid & 63;
  const int wr = w >> 1, wc = w & 1;
  const int lrow = l & 15, lkg = l >> 4;
  const int m0 = blockIdx.x * 128, n0 = blockIdx.y * 128;

  f32x4 acc[4][4] = {};
  stage_rows<4>(A, m0, 0, sA[0], tid);
  stage_rows<4>(B, n0, 0, sB[0], tid);

  for (int it = 0; it < 16; ++it) {
    __syncthreads();
    const int cur = it & 1;
    if (it < 15) {
      const int k0 = (it + 1) * BK;
      stage_rows<4>(A, m0, k0, sA[cur ^ 1], tid);
      stage_rows<4>(B, n0, k0, sB[cur ^ 1], tid);
    }
#pragma unroll
    for (int ks = 0; ks < 2; ++ks) {
      f16x8 af[4], bf[4];
#pragma unroll
      for (int fi = 0; fi < 4; ++fi) {
        int row = wr * 64 + fi * 16 + lrow;
        int pkg = (ks * 4 + lkg) ^ (row & 7);
        af[fi] = *(const f16x8*)&sA[cur][row * BK + pkg * 8];
      }
#pragma unroll
      for (int fj = 0; fj < 4; ++fj) {
        int row = wc * 64 + fj * 16 + lrow;
        int pkg = (ks * 4 + lkg) ^ (row & 7);
        bf[fj] = *(const f16x8*)&sB[cur][row * BK + pkg * 8];
      }
#pragma unroll
      for (int fi = 0; fi < 4; ++fi)
#pragma unroll
        for (int fj = 0; fj < 4; ++fj)
          acc[fi][fj] = __builtin_amdgcn_mfma_f32_16x16x32_f16(af[fi], bf[fj], acc[fi][fj], 0, 0, 0);
    }
  }
#pragma unroll
  for (int fi = 0; fi < 4; ++fi)
#pragma unroll
    for (int fj = 0; fj < 4; ++fj)
#pragma unroll
      for (int r = 0; r < 4; ++r) {
        int row = m0 + wr * 64 + fi * 16 + lkg * 4 + r;
        int col = n0 + wc * 64 + fj * 16 + lrow;
        C[(size_t)row * N + col] = acc[fi][fj][r] + bias[col];
      }
}

// ---------- encoder GEMM (sequential 3-pass, 64x64; off critical path) ----------
__device__ __forceinline__ void stage_tile(const f16* __restrict__ g, int r0, int k0,
                                           f16* sdst, int tid) {
  stage_rows<2>(g, r0, k0, sdst, tid);
}

__global__ __launch_bounds__(256) void k_gemm3(const f16* __restrict__ Ah, const f16* __restrict__ Al,
                                               const f16* __restrict__ Bh, const f16* __restrict__ Bl,
                                               float* __restrict__ C, const float* __restrict__ bias,
                                               int N) {
  __shared__ alignas(16) f16 sA[2][BM * BK];
  __shared__ alignas(16) f16 sB[2][BN * BK];
  const int tid = threadIdx.x;
  const int w = tid >> 6, l = tid & 63;
  const int wr = w >> 1, wc = w & 1;
  const int lrow = l & 15, lkg = l >> 4;
  const int m0 = blockIdx.x * BM, n0 = blockIdx.y * BN;
  const int TOT = 48;

  f32x4 acc[2][2] = {};
  stage_tile(Ah, m0, 0, sA[0], tid);
  stage_tile(Bh, n0, 0, sB[0], tid);

  for (int it = 0; it < TOT; ++it) {
    __syncthreads();
    const int cur = it & 1;
    if (it + 1 < TOT) {
      const int nx = it + 1;
      const f16* An = (nx >= 32) ? Al : Ah;
      const f16* Bn = ((nx >> 4) == 1) ? Bl : Bh;
      const int k0 = (nx & 15) * BK;
      stage_tile(An, m0, k0, sA[cur ^ 1], tid);
      stage_tile(Bn, n0, k0, sB[cur ^ 1], tid);
    }
#pragma unroll
    for (int ks = 0; ks < 2; ++ks) {
      f16x8 af[2], bf[2];
#pragma unroll
      for (int fi = 0; fi < 2; ++fi) {
        int row = wr * 32 + fi * 16 + lrow;
        int pkg = (ks * 4 + lkg) ^ (row & 7);
        af[fi] = *(const f16x8*)&sA[cur][row * BK + pkg * 8];
      }
#pragma unroll
      for (int fj = 0; fj < 2; ++fj) {
        int row = wc * 32 + fj * 16 + lrow;
        int pkg = (ks * 4 + lkg) ^ (row & 7);
        bf[fj] = *(const f16x8*)&sB[cur][row * BK + pkg * 8];
      }
#pragma unroll
      for (int fi = 0; fi < 2; ++fi)
#pragma unroll
        for (int fj = 0; fj < 2; ++fj)
          acc[fi][fj] = __builtin_amdgcn_mfma_f32_16x16x32_f16(af[fi], bf[fj], acc[fi][fj], 0, 0, 0);
    }
  }
#pragma unroll
  for (int fi = 0; fi < 2; ++fi)
#pragma unroll
    for (int fj = 0; fj < 2; ++fj)
#pragma unroll
      for (int r = 0; r < 4; ++r) {
        int row = m0 + wr * 32 + fi * 16 + lkg * 4 + r;
        int col = n0 + wc * 32 + fj * 16 + lrow;
        C[(size_t)row * N + col] = acc[fi][fj][r] + (bias ? bias[col] : 0.f);
      }
}

// ---------- block-wide sum of 2 values (256 threads) ----------
__device__ __forceinline__ void block_sum2(float& a, float& b) {
#pragma unroll
  for (int o = 32; o > 0; o >>= 1) { a += __shfl_down(a, o, 64); b += __shfl_down(b, o, 64); }
  __shared__ float sa[4], sb[4];
  int w = threadIdx.x >> 6, l = threadIdx.x & 63;
  if (l == 0) { sa[w] = a; sb[w] = b; }
  __syncthreads();
  a = sa[0] + sa[1] + sa[2] + sa[3];
  b = sb[0] + sb[1] + sb[2] + sb[3];
}

__device__ __forceinline__ void split_store(float v, f16* hi, f16* lo, size_t idx) {
  f16 h = (f16)v;
  hi[idx] = h;
  lo[idx] = (f16)(v - (float)h);
}

// ---------- GRU gate + LN fused. One block per batch row. ----------
__global__ __launch_bounds__(256) void k_gru_gate(const float* __restrict__ gi, const float* __restrict__ gh,
                                                  float* __restrict__ hnf,
                                                  f16* __restrict__ hnhi, f16* __restrict__ hnlo,
                                                  f16* __restrict__ xhi, f16* __restrict__ xlo,
                                                  const float* __restrict__ bih, const float* __restrict__ bhh,
                                                  const float* __restrict__ lng, const float* __restrict__ lnb,
                                                  f16* __restrict__ outp, long ostride) {
  int m = blockIdx.x, tid = threadIdx.x;
  float h[4];
  float s1 = 0.f, s2 = 0.f;
#pragma unroll
  for (int k = 0; k < 4; ++k) {
    int c = tid + k * 256;
    size_t g0 = (size_t)m * (3 * Hh) + c;
    float rr  = (gi[g0]          + bih[c])          + (gh[g0]          + bhh[c]);
    float zz  = (gi[g0 + Hh]     + bih[Hh + c])     + (gh[g0 + Hh]     + bhh[Hh + c]);
    float in_ =  gi[g0 + 2 * Hh] + bih[2 * Hh + c];
    float hn_ =  gh[g0 + 2 * Hh] + bhh[2 * Hh + c];
    float r = 1.f / (1.f + expf(-rr));
    float z = 1.f / (1.f + expf(-zz));
    float n = tanhf(in_ + r * hn_);
    float hp = hnf[(size_t)m * Hh + c];
    float hv = (1.f - z) * n + z * hp;
    h[k] = hv;
    split_store(hv, xhi, xlo, (size_t)m * Hh + c);
    if (outp) outp[(size_t)m * ostride + c] = (f16)hv;
    s1 += hv; s2 += hv * hv;
  }
  block_sum2(s1, s2);
  float mean = s1 * (1.f / Hh);
  float var  = s2 * (1.f / Hh) - mean * mean;
  float rs   = rsqrtf(var + 1e-5f);
#pragma unroll
  for (int k = 0; k < 4; ++k) {
    int c = tid + k * 256;
    float v = (h[k] - mean) * rs * lng[c] + lnb[c];
    hnf[(size_t)m * Hh + c] = v;
    split_store(v, hnhi, hnlo, (size_t)m * Hh + c);
  }
}

// ---------- LN + ReLU -> f16 (hi or hi+lo) ----------
__global__ __launch_bounds__(256) void k_ln_relu(const float* __restrict__ pre,
                                                 const float* __restrict__ g, const float* __restrict__ b,
                                                 f16* __restrict__ hi, f16* __restrict__ lo) {
  int m = blockIdx.x, tid = threadIdx.x;
  float v[4]; float s1 = 0.f, s2 = 0.f;
#pragma unroll
  for (int k = 0; k < 4; ++k) {
    int c = tid + k * 256;
    float x = pre[(size_t)m * Hh + c];
    v[k] = x; s1 += x; s2 += x * x;
  }
  block_sum2(s1, s2);
  float mean = s1 * (1.f / Hh);
  float var  = s2 * (1.f / Hh) - mean * mean;
  float rs   = rsqrtf(var + 1e-5f);
#pragma unroll
  for (int k = 0; k < 4; ++k) {
    int c = tid + k * 256;
    float y = (v[k] - mean) * rs * g[c] + b[c];
    y = y > 0.f ? y : 0.f;
    f16 hh = (f16)y;
    hi[(size_t)m * Hh + c] = hh;
    if (lo) lo[(size_t)m * Hh + c] = (f16)(y - (float)hh);
  }
}

extern "C" void kernel_launch(void* const* d_in, const int* in_sizes, int n_in,
                              void* d_out, int out_size, void* d_ws, size_t ws_size,
                              hipStream_t stream) {
  (void)in_sizes; (void)n_in; (void)out_size; (void)ws_size;
  const float* x     = (const float*)d_in[0];
  const float* encW1 = (const float*)d_in[1];
  const float* encb1 = (const float*)d_in[2];
  const float* ln1g  = (const float*)d_in[3];
  const float* ln1b  = (const float*)d_in[4];
  const float* encW2 = (const float*)d_in[5];
  const float* encb2 = (const float*)d_in[6];
  const float* ln2g  = (const float*)d_in[7];
  const float* ln2b  = (const float*)d_in[8];
  const float* Wih0  = (const float*)d_in[9];
  const float* Whh0  = (const float*)d_in[10];
  const float* bih0  = (const float*)d_in[11];
  const float* bhh0  = (const float*)d_in[12];
  const float* Wih1  = (const float*)d_in[13];
  const float* Whh1  = (const float*)d_in[14];
  const float* bih1  = (const float*)d_in[15];
  const float* bhh1  = (const float*)d_in[16];
  const float* hng   = (const float*)d_in[17];
  const float* hnb   = (const float*)d_in[18];
  const float* pW1   = (const float*)d_in[19];
  const float* pb1   = (const float*)d_in[20];
  const float* plng  = (const float*)d_in[21];
  const float* plnb  = (const float*)d_in[22];
  const float* pW2   = (const float*)d_in[23];
  const float* pb2   = (const float*)d_in[24];

  char* p = (char*)d_ws;
  auto alloc = [&](size_t bytes) { void* r = (void*)p; p += (bytes + 255) & ~(size_t)255; return r; };
  auto fpair = [&](size_t n, f16** hi, f16** lo) {
    *hi = (f16*)alloc(n * 2); *lo = (f16*)alloc(n * 2);
  };
  f16 *We1h, *We1l, *We2h, *We2l, *Wih0h, *Wih0l, *Whh0h, *Whh0l, *Wih1h, *Wih1l, *Whh1h, *Whh1l;
  fpair((size_t)Hh * Dd, &We1h, &We1l);
  fpair((size_t)Hh * Hh, &We2h, &We2l);
  fpair((size_t)3 * Hh * Hh, &Wih0h, &Wih0l);
  fpair((size_t)3 * Hh * Hh, &Whh0h, &Whh0l);
  fpair((size_t)3 * Hh * Hh, &Wih1h, &Wih1l);
  fpair((size_t)3 * Hh * Hh, &Whh1h, &Whh1l);
  f16* pW1h = (f16*)alloc((size_t)Hh * Hh * 2);
  f16* pW2h = (f16*)alloc((size_t)Dd * Hh * 2);
  f16 *xhi, *xlo, *curh, *curl, *x1h, *x1l, *hn0h, *hn0l, *hn1h, *hn1l;
  fpair((size_t)Bb * Dd, &xhi, &xlo);
  fpair((size_t)Bb * Hh, &curh, &curl);
  fpair((size_t)Bb * Hh, &x1h, &x1l);
  fpair((size_t)Bb * Hh, &hn0h, &hn0l);
  fpair((size_t)Bb * Hh, &hn1h, &hn1l);
  float* hn0f = (float*)alloc((size_t)Bb * Hh * 4);
  float* hn1f = (float*)alloc((size_t)Bb * Hh * 4);
  float* gif  = (float*)alloc((size_t)Bb * 3 * Hh * 4);
  float* ghf  = (float*)alloc((size_t)Bb * 3 * Hh * 4);
  f16* outsh  = (f16*)alloc((size_t)Bb * T_STEPS * Hh * 2);
  f16* ph     = outsh;          // proj intermediate aliases outsh (dead by then)... NOT: outsh read by GEMM1 while ph written by ln_relu AFTER. Distinct needed? GEMM1 reads outsh fully -> pre; ln_relu reads pre writes ph. outsh dead after GEMM1 -> alias safe.
  float* pre  = (float*)d_out;  // d_out doubles as f32 [25600,1024] proj scratch

  auto spl = [&](const float* s, f16* hi, f16* lo, int n) {
    hipLaunchKernelGGL(k_f32_split, dim3((n / 4 + 255) / 256), dim3(256), 0, stream, s, hi, lo, n);
  };
  auto conv = [&](const float* s, f16* d, int n) {
    hipLaunchKernelGGL(k_f32_to_f16, dim3((n / 4 + 255) / 256), dim3(256), 0, stream, s, d, n);
  };
  spl(x, xhi, xlo, Bb * Dd);
  spl(encW1, We1h, We1l, Hh * Dd);
  spl(encW2, We2h, We2l, Hh * Hh);
  spl(Wih0, Wih0h, Wih0l, 3 * Hh * Hh);
  spl(Whh0, Whh0h, Whh0l, 3 * Hh * Hh);
  spl(Wih1, Wih1h, Wih1l, 3 * Hh * Hh);
  spl(Whh1, Whh1h, Whh1l, 3 * Hh * Hh);
  conv(pW1, pW1h, Hh * Hh);
  conv(pW2, pW2h, Dd * Hh);
  hipLaunchKernelGGL(k_init_hn, dim3(Bb), dim3(256), 0, stream, hnb, hn0f, hn1f, hn0h, hn0l, hn1h, hn1l);

  // ---------- encoder (split precision) ----------
  hipLaunchKernelGGL(k_gemm3, dim3(Bb / BM, Hh / BN), dim3(256), 0, stream,
                     xhi, xlo, We1h, We1l, gif, encb1, Hh);
  hipLaunchKernelGGL(k_ln_relu, dim3(Bb), dim3(256), 0, stream, gif, ln1g, ln1b, x1h, x1l);
  hipLaunchKernelGGL(k_gemm3, dim3(Bb / BM, Hh / BN), dim3(256), 0, stream,
                     x1h, x1l, We2h, We2l, gif, encb2, Hh);
  hipLaunchKernelGGL(k_ln_relu, dim3(Bb), dim3(256), 0, stream, gif, ln2g, ln2b, curh, curl);

  // ---------- GRU: 100 steps x 2 layers, fused-3 split GEMMs ----------
  for (int t = 0; t < T_STEPS; ++t) {
    hipLaunchKernelGGL(k_gru_gemm, dim3(Bb / FBM, 3072 / FBN, 2), dim3(256), 0, stream,
                       curh, curl, Wih0h, Wih0l, gif, hn0h, hn0l, Whh0h, Whh0l, ghf);
    hipLaunchKernelGGL(k_gru_gate, dim3(Bb), dim3(256), 0, stream,
                       gif, ghf, hn0f, hn0h, hn0l, x1h, x1l, bih0, bhh0, hng, hnb,
                       (f16*)nullptr, (long)0);
    hipLaunchKernelGGL(k_gru_gemm, dim3(Bb / FBM, 3072 / FBN, 2), dim3(256), 0, stream,
                       x1h, x1l, Wih1h, Wih1l, gif, hn1h, hn1l, Whh1h, Whh1l, ghf);
    hipLaunchKernelGGL(k_gru_gate, dim3(Bb), dim3(256), 0, stream,
                       gif, ghf, hn1f, hn1h, hn1l, curh, curl, bih1, bhh1, hng, hnb,
                       outsh + (size_t)t * Hh, (long)T_STEPS * Hh);
  }

  // ---------- projection (single f16, 128x128 tiles) ----------
  hipLaunchKernelGGL(k_gemm_big, dim3(Bb * T_STEPS / 128, Hh / 128), dim3(256), 0, stream,
                     outsh, pW1h, pre, pb1, Hh);
  hipLaunchKernelGGL(k_ln_relu, dim3(Bb * T_STEPS), dim3(256), 0, stream, pre, plng, plnb,
                     ph, (f16*)nullptr);
  hipLaunchKernelGGL(k_gemm_big, dim3(Bb * T_STEPS / 128, Dd / 128), dim3(256), 0, stream,
                     ph, pW2h, (float*)d_out, pb2, Dd);
}

// Round 4
// 4691.789 us; speedup vs baseline: 1.8181x; 1.5649x over previous
//
#include <hip/hip_runtime.h>
#include <stdint.h>

// Problem constants (fixed by the reference)
#define T_STEPS 100
#define Bb 256
#define Hh 1024
#define Dd 1024
#define BM 64
#define BN 64
#define BK 64

typedef _Float16 f16;
typedef _Float16 f16x8 __attribute__((ext_vector_type(8)));
typedef _Float16 f16x4 __attribute__((ext_vector_type(4)));
typedef float    f32x4 __attribute__((ext_vector_type(4)));

// ---------- f32 -> (hi,lo) f16 split: v = hi + lo + O(2^-22 |v|) ----------
__global__ __launch_bounds__(256) void k_f32_split(const float* __restrict__ s,
                                                   f16* __restrict__ hi, f16* __restrict__ lo, int n) {
  int i = (blockIdx.x * blockDim.x + threadIdx.x) * 4;
  if (i >= n) return;
  float4 v = *(const float4*)(s + i);
  f16x4 h = { (f16)v.x, (f16)v.y, (f16)v.z, (f16)v.w };
  f16x4 L = { (f16)(v.x - (float)h.x), (f16)(v.y - (float)h.y),
              (f16)(v.z - (float)h.z), (f16)(v.w - (float)h.w) };
  *(f16x4*)(hi + i) = h;
  *(f16x4*)(lo + i) = L;
}

__global__ __launch_bounds__(256) void k_f32_to_f16(const float* __restrict__ s,
                                                    f16* __restrict__ d, int n) {
  int i = (blockIdx.x * blockDim.x + threadIdx.x) * 4;
  if (i >= n) return;
  float4 v = *(const float4*)(s + i);
  f16x4 o = { (f16)v.x, (f16)v.y, (f16)v.z, (f16)v.w };
  *(f16x4*)(d + i) = o;
}

// ---------- init: hn = LN(0) = ln_bias ----------
__global__ __launch_bounds__(256) void k_init_hn(const float* __restrict__ lnb,
                                                 float* __restrict__ hn0f, float* __restrict__ hn1f,
                                                 f16* __restrict__ h0hi, f16* __restrict__ h0lo,
                                                 f16* __restrict__ h1hi, f16* __restrict__ h1lo) {
  int m = blockIdx.x, tid = threadIdx.x;
  for (int k = 0; k < 4; ++k) {
    int c = tid + k * 256;
    float v = lnb[c];
    f16 h = (f16)v; f16 L = (f16)(v - (float)h);
    size_t idx = (size_t)m * Hh + c;
    hn0f[idx] = v; hn1f[idx] = v;
    h0hi[idx] = h; h0lo[idx] = L;
    h1hi[idx] = h; h1lo[idx] = L;
  }
}

// ---------- shared staging helper: NCH 16B-chunks/thread, K stride fixed 1024 ----------
// XOR-swizzle (rule #21): linear LDS dest + inverse-swizzled global source; the
// ds_read applies the same involution. 2-way conflicts only (free, m136).
template <int NCH>
__device__ __forceinline__ void stage_rows(const f16* __restrict__ g, int r0, int k0,
                                           f16* sdst, int tid) {
#pragma unroll
  for (int i = 0; i < NCH; ++i) {
    int slot = i * 256 + tid;
    int row  = slot >> 3;
    int pkg  = slot & 7;
    int lg   = pkg ^ (row & 7);
    const f16* src = g + (size_t)(r0 + row) * 1024 + k0 + lg * 8;
    f16* dst = sdst + (size_t)slot * 8;
    __builtin_amdgcn_global_load_lds((const __attribute__((address_space(1))) void*)src,
                                     (__attribute__((address_space(3))) void*)dst, 16, 0, 0);
  }
}

// ---------- GRU dual GEMM, fused 3-pass split precision, counted-vmcnt pipeline ----------
// C[256,3072] = A[256,1024] @ W[3072,1024]^T, (hi,lo) f16 pairs:
// acc += Ah*Bh + Ah*Bl + Al*Bh per staged K-tile. Tile 64x96, 4 waves (2x2),
// wave-tile 32x48. 256 WGs = 1/CU. LDS 120 KB = 3 buffers x 40 KB.
// T4 pipeline: 3 tiles in flight, s_waitcnt vmcnt(20) per iter (never 0 until
// drain), raw s_barrier pair. T1 variant: XCD-chunked remap pins each XCD's
// 3.2 MB weight slice in its 4 MB L2 across all 100 steps.
#define FBM 64
#define FBN 96
__global__ __launch_bounds__(256) void k_gru_gemm(
    const f16* __restrict__ A0h, const f16* __restrict__ A0l,
    const f16* __restrict__ B0h, const f16* __restrict__ B0l, float* __restrict__ C0,
    const f16* __restrict__ A1h, const f16* __restrict__ A1l,
    const f16* __restrict__ B1h, const f16* __restrict__ B1l, float* __restrict__ C1) {
  // bijective remap: xcd = wgid&7 owns y-panels [4*xcd, 4*xcd+4) for both z
  const int wgid = blockIdx.x;
  const int xcd = wgid & 7, idx = wgid >> 3;
  const int bx = idx & 3, yp = (idx >> 2) & 3, bz = idx >> 4;
  const int by = xcd * 4 + yp;

  const f16* Ah = bz ? A1h : A0h;
  const f16* Al = bz ? A1l : A0l;
  const f16* Bh = bz ? B1h : B0h;
  const f16* Bl = bz ? B1l : B0l;
  float*     C  = bz ? C1  : C0;

  __shared__ alignas(16) f16 sAh[3][FBM * BK];
  __shared__ alignas(16) f16 sAl[3][FBM * BK];
  __shared__ alignas(16) f16 sBh[3][FBN * BK];
  __shared__ alignas(16) f16 sBl[3][FBN * BK];

  const int tid = threadIdx.x;
  const int w = tid >> 6, l = tid & 63;
  const int wr = w >> 1, wc = w & 1;
  const int lrow = l & 15, lkg = l >> 4;
  const int m0 = bx * FBM, n0 = by * FBN;

  f32x4 acc[2][3] = {};

  // prologue: 3 tiles in flight (30 VMEM instrs/wave outstanding)
#pragma unroll
  for (int pt = 0; pt < 3; ++pt) {
    stage_rows<2>(Ah, m0, pt * BK, sAh[pt], tid);
    stage_rows<2>(Al, m0, pt * BK, sAl[pt], tid);
    stage_rows<3>(Bh, n0, pt * BK, sBh[pt], tid);
    stage_rows<3>(Bl, n0, pt * BK, sBl[pt], tid);
  }

#pragma unroll
  for (int it = 0; it < 16; ++it) {
    const int cur = it % 3;
    // wait for the OLDEST tile's 10 loads only (2 newer tiles stay in flight)
    if (it <= 13)      asm volatile("s_waitcnt vmcnt(20)" ::: "memory");
    else if (it == 14) asm volatile("s_waitcnt vmcnt(10)" ::: "memory");
    else               asm volatile("s_waitcnt vmcnt(0)" ::: "memory");
    __builtin_amdgcn_s_barrier();   // all waves' tile-it loads now in LDS

    // ds_read the whole tile into registers (20 x b128 per wave)
    f16x8 ah[2][2], al[2][2], bh[2][3], bl[2][3];
#pragma unroll
    for (int ks = 0; ks < 2; ++ks) {
#pragma unroll
      for (int fi = 0; fi < 2; ++fi) {
        int row = wr * 32 + fi * 16 + lrow;
        int pkg = (ks * 4 + lkg) ^ (row & 7);
        ah[ks][fi] = *(const f16x8*)&sAh[cur][row * BK + pkg * 8];
        al[ks][fi] = *(const f16x8*)&sAl[cur][row * BK + pkg * 8];
      }
#pragma unroll
      for (int fj = 0; fj < 3; ++fj) {
        int row = wc * 48 + fj * 16 + lrow;
        int pkg = (ks * 4 + lkg) ^ (row & 7);
        bh[ks][fj] = *(const f16x8*)&sBh[cur][row * BK + pkg * 8];
        bl[ks][fj] = *(const f16x8*)&sBl[cur][row * BK + pkg * 8];
      }
    }
    asm volatile("s_waitcnt lgkmcnt(0)" ::: "memory");  // reads landed in regs
    __builtin_amdgcn_s_barrier();   // all waves done reading buf[cur]

    // overwrite the freed buffer with tile it+3 (loads stay in flight past MFMA)
    if (it < 13) {
      const int k0 = (it + 3) * BK;
      stage_rows<2>(Ah, m0, k0, sAh[cur], tid);
      stage_rows<2>(Al, m0, k0, sAl[cur], tid);
      stage_rows<3>(Bh, n0, k0, sBh[cur], tid);
      stage_rows<3>(Bl, n0, k0, sBl[cur], tid);
    }

    // MFMA cluster (register-only), same accumulation order as round 2/3
#pragma unroll
    for (int ks = 0; ks < 2; ++ks)
#pragma unroll
      for (int fi = 0; fi < 2; ++fi)
#pragma unroll
        for (int fj = 0; fj < 3; ++fj) {
          acc[fi][fj] = __builtin_amdgcn_mfma_f32_16x16x32_f16(ah[ks][fi], bh[ks][fj], acc[fi][fj], 0, 0, 0);
          acc[fi][fj] = __builtin_amdgcn_mfma_f32_16x16x32_f16(ah[ks][fi], bl[ks][fj], acc[fi][fj], 0, 0, 0);
          acc[fi][fj] = __builtin_amdgcn_mfma_f32_16x16x32_f16(al[ks][fi], bh[ks][fj], acc[fi][fj], 0, 0, 0);
        }
  }

  // C/D layout: col = lane&15, row = (lane>>4)*4 + r  [m89]
#pragma unroll
  for (int fi = 0; fi < 2; ++fi)
#pragma unroll
    for (int fj = 0; fj < 3; ++fj)
#pragma unroll
      for (int r = 0; r < 4; ++r) {
        int row = m0 + wr * 32 + fi * 16 + lkg * 4 + r;
        int col = n0 + wc * 48 + fj * 16 + lrow;
        C[(size_t)row * 3072 + col] = acc[fi][fj][r];
      }
}

// ---------- big single-pass GEMM (projection): 128x128 tile, m97 structure ----------
__global__ __launch_bounds__(256) void k_gemm_big(const f16* __restrict__ A, const f16* __restrict__ B,
                                                  float* __restrict__ C, const float* __restrict__ bias,
                                                  int N) {
  __shared__ alignas(16) f16 sA[2][128 * BK];
  __shared__ alignas(16) f16 sB[2][128 * BK];
  const int tid = threadIdx.x;
  const int w = tid >> 6, l = tid & 63;
  const int wr = w >> 1, wc = w & 1;
  const int lrow = l & 15, lkg = l >> 4;
  const int m0 = blockIdx.x * 128, n0 = blockIdx.y * 128;

  f32x4 acc[4][4] = {};
  stage_rows<4>(A, m0, 0, sA[0], tid);
  stage_rows<4>(B, n0, 0, sB[0], tid);

  for (int it = 0; it < 16; ++it) {
    __syncthreads();
    const int cur = it & 1;
    if (it < 15) {
      const int k0 = (it + 1) * BK;
      stage_rows<4>(A, m0, k0, sA[cur ^ 1], tid);
      stage_rows<4>(B, n0, k0, sB[cur ^ 1], tid);
    }
#pragma unroll
    for (int ks = 0; ks < 2; ++ks) {
      f16x8 af[4], bf[4];
#pragma unroll
      for (int fi = 0; fi < 4; ++fi) {
        int row = wr * 64 + fi * 16 + lrow;
        int pkg = (ks * 4 + lkg) ^ (row & 7);
        af[fi] = *(const f16x8*)&sA[cur][row * BK + pkg * 8];
      }
#pragma unroll
      for (int fj = 0; fj < 4; ++fj) {
        int row = wc * 64 + fj * 16 + lrow;
        int pkg = (ks * 4 + lkg) ^ (row & 7);
        bf[fj] = *(const f16x8*)&sB[cur][row * BK + pkg * 8];
      }
#pragma unroll
      for (int fi = 0; fi < 4; ++fi)
#pragma unroll
        for (int fj = 0; fj < 4; ++fj)
          acc[fi][fj] = __builtin_amdgcn_mfma_f32_16x16x32_f16(af[fi], bf[fj], acc[fi][fj], 0, 0, 0);
    }
  }
#pragma unroll
  for (int fi = 0; fi < 4; ++fi)
#pragma unroll
    for (int fj = 0; fj < 4; ++fj)
#pragma unroll
      for (int r = 0; r < 4; ++r) {
        int row = m0 + wr * 64 + fi * 16 + lkg * 4 + r;
        int col = n0 + wc * 64 + fj * 16 + lrow;
        C[(size_t)row * N + col] = acc[fi][fj][r] + bias[col];
      }
}

// ---------- encoder GEMM (sequential 3-pass, 64x64; off critical path) ----------
__device__ __forceinline__ void stage_tile(const f16* __restrict__ g, int r0, int k0,
                                           f16* sdst, int tid) {
  stage_rows<2>(g, r0, k0, sdst, tid);
}

__global__ __launch_bounds__(256) void k_gemm3(const f16* __restrict__ Ah, const f16* __restrict__ Al,
                                               const f16* __restrict__ Bh, const f16* __restrict__ Bl,
                                               float* __restrict__ C, const float* __restrict__ bias,
                                               int N) {
  __shared__ alignas(16) f16 sA[2][BM * BK];
  __shared__ alignas(16) f16 sB[2][BN * BK];
  const int tid = threadIdx.x;
  const int w = tid >> 6, l = tid & 63;
  const int wr = w >> 1, wc = w & 1;
  const int lrow = l & 15, lkg = l >> 4;
  const int m0 = blockIdx.x * BM, n0 = blockIdx.y * BN;
  const int TOT = 48;

  f32x4 acc[2][2] = {};
  stage_tile(Ah, m0, 0, sA[0], tid);
  stage_tile(Bh, n0, 0, sB[0], tid);

  for (int it = 0; it < TOT; ++it) {
    __syncthreads();
    const int cur = it & 1;
    if (it + 1 < TOT) {
      const int nx = it + 1;
      const f16* An = (nx >= 32) ? Al : Ah;
      const f16* Bn = ((nx >> 4) == 1) ? Bl : Bh;
      const int k0 = (nx & 15) * BK;
      stage_tile(An, m0, k0, sA[cur ^ 1], tid);
      stage_tile(Bn, n0, k0, sB[cur ^ 1], tid);
    }
#pragma unroll
    for (int ks = 0; ks < 2; ++ks) {
      f16x8 af[2], bf[2];
#pragma unroll
      for (int fi = 0; fi < 2; ++fi) {
        int row = wr * 32 + fi * 16 + lrow;
        int pkg = (ks * 4 + lkg) ^ (row & 7);
        af[fi] = *(const f16x8*)&sA[cur][row * BK + pkg * 8];
      }
#pragma unroll
      for (int fj = 0; fj < 2; ++fj) {
        int row = wc * 32 + fj * 16 + lrow;
        int pkg = (ks * 4 + lkg) ^ (row & 7);
        bf[fj] = *(const f16x8*)&sB[cur][row * BK + pkg * 8];
      }
#pragma unroll
      for (int fi = 0; fi < 2; ++fi)
#pragma unroll
        for (int fj = 0; fj < 2; ++fj)
          acc[fi][fj] = __builtin_amdgcn_mfma_f32_16x16x32_f16(af[fi], bf[fj], acc[fi][fj], 0, 0, 0);
    }
  }
#pragma unroll
  for (int fi = 0; fi < 2; ++fi)
#pragma unroll
    for (int fj = 0; fj < 2; ++fj)
#pragma unroll
      for (int r = 0; r < 4; ++r) {
        int row = m0 + wr * 32 + fi * 16 + lkg * 4 + r;
        int col = n0 + wc * 32 + fj * 16 + lrow;
        C[(size_t)row * N + col] = acc[fi][fj][r] + (bias ? bias[col] : 0.f);
      }
}

// ---------- block-wide sum of 2 values (256 threads) ----------
__device__ __forceinline__ void block_sum2(float& a, float& b) {
#pragma unroll
  for (int o = 32; o > 0; o >>= 1) { a += __shfl_down(a, o, 64); b += __shfl_down(b, o, 64); }
  __shared__ float sa[4], sb[4];
  int w = threadIdx.x >> 6, l = threadIdx.x & 63;
  if (l == 0) { sa[w] = a; sb[w] = b; }
  __syncthreads();
  a = sa[0] + sa[1] + sa[2] + sa[3];
  b = sb[0] + sb[1] + sb[2] + sb[3];
}

__device__ __forceinline__ void split_store(float v, f16* hi, f16* lo, size_t idx) {
  f16 h = (f16)v;
  hi[idx] = h;
  lo[idx] = (f16)(v - (float)h);
}

// ---------- GRU gate + LN fused. One block per batch row. ----------
__global__ __launch_bounds__(256) void k_gru_gate(const float* __restrict__ gi, const float* __restrict__ gh,
                                                  float* __restrict__ hnf,
                                                  f16* __restrict__ hnhi, f16* __restrict__ hnlo,
                                                  f16* __restrict__ xhi, f16* __restrict__ xlo,
                                                  const float* __restrict__ bih, const float* __restrict__ bhh,
                                                  const float* __restrict__ lng, const float* __restrict__ lnb,
                                                  f16* __restrict__ outp, long ostride) {
  int m = blockIdx.x, tid = threadIdx.x;
  float h[4];
  float s1 = 0.f, s2 = 0.f;
#pragma unroll
  for (int k = 0; k < 4; ++k) {
    int c = tid + k * 256;
    size_t g0 = (size_t)m * (3 * Hh) + c;
    float rr  = (gi[g0]          + bih[c])          + (gh[g0]          + bhh[c]);
    float zz  = (gi[g0 + Hh]     + bih[Hh + c])     + (gh[g0 + Hh]     + bhh[Hh + c]);
    float in_ =  gi[g0 + 2 * Hh] + bih[2 * Hh + c];
    float hn_ =  gh[g0 + 2 * Hh] + bhh[2 * Hh + c];
    float r = 1.f / (1.f + expf(-rr));
    float z = 1.f / (1.f + expf(-zz));
    float n = tanhf(in_ + r * hn_);
    float hp = hnf[(size_t)m * Hh + c];
    float hv = (1.f - z) * n + z * hp;
    h[k] = hv;
    split_store(hv, xhi, xlo, (size_t)m * Hh + c);
    if (outp) outp[(size_t)m * ostride + c] = (f16)hv;
    s1 += hv; s2 += hv * hv;
  }
  block_sum2(s1, s2);
  float mean = s1 * (1.f / Hh);
  float var  = s2 * (1.f / Hh) - mean * mean;
  float rs   = rsqrtf(var + 1e-5f);
#pragma unroll
  for (int k = 0; k < 4; ++k) {
    int c = tid + k * 256;
    float v = (h[k] - mean) * rs * lng[c] + lnb[c];
    hnf[(size_t)m * Hh + c] = v;
    split_store(v, hnhi, hnlo, (size_t)m * Hh + c);
  }
}

// ---------- LN + ReLU -> f16 (hi or hi+lo) ----------
__global__ __launch_bounds__(256) void k_ln_relu(const float* __restrict__ pre,
                                                 const float* __restrict__ g, const float* __restrict__ b,
                                                 f16* __restrict__ hi, f16* __restrict__ lo) {
  int m = blockIdx.x, tid = threadIdx.x;
  float v[4]; float s1 = 0.f, s2 = 0.f;
#pragma unroll
  for (int k = 0; k < 4; ++k) {
    int c = tid + k * 256;
    float x = pre[(size_t)m * Hh + c];
    v[k] = x; s1 += x; s2 += x * x;
  }
  block_sum2(s1, s2);
  float mean = s1 * (1.f / Hh);
  float var  = s2 * (1.f / Hh) - mean * mean;
  float rs   = rsqrtf(var + 1e-5f);
#pragma unroll
  for (int k = 0; k < 4; ++k) {
    int c = tid + k * 256;
    float y = (v[k] - mean) * rs * g[c] + b[c];
    y = y > 0.f ? y : 0.f;
    f16 hh = (f16)y;
    hi[(size_t)m * Hh + c] = hh;
    if (lo) lo[(size_t)m * Hh + c] = (f16)(y - (float)hh);
  }
}

extern "C" void kernel_launch(void* const* d_in, const int* in_sizes, int n_in,
                              void* d_out, int out_size, void* d_ws, size_t ws_size,
                              hipStream_t stream) {
  (void)in_sizes; (void)n_in; (void)out_size; (void)ws_size;
  const float* x     = (const float*)d_in[0];
  const float* encW1 = (const float*)d_in[1];
  const float* encb1 = (const float*)d_in[2];
  const float* ln1g  = (const float*)d_in[3];
  const float* ln1b  = (const float*)d_in[4];
  const float* encW2 = (const float*)d_in[5];
  const float* encb2 = (const float*)d_in[6];
  const float* ln2g  = (const float*)d_in[7];
  const float* ln2b  = (const float*)d_in[8];
  const float* Wih0  = (const float*)d_in[9];
  const float* Whh0  = (const float*)d_in[10];
  const float* bih0  = (const float*)d_in[11];
  const float* bhh0  = (const float*)d_in[12];
  const float* Wih1  = (const float*)d_in[13];
  const float* Whh1  = (const float*)d_in[14];
  const float* bih1  = (const float*)d_in[15];
  const float* bhh1  = (const float*)d_in[16];
  const float* hng   = (const float*)d_in[17];
  const float* hnb   = (const float*)d_in[18];
  const float* pW1   = (const float*)d_in[19];
  const float* pb1   = (const float*)d_in[20];
  const float* plng  = (const float*)d_in[21];
  const float* plnb  = (const float*)d_in[22];
  const float* pW2   = (const float*)d_in[23];
  const float* pb2   = (const float*)d_in[24];

  char* p = (char*)d_ws;
  auto alloc = [&](size_t bytes) { void* r = (void*)p; p += (bytes + 255) & ~(size_t)255; return r; };
  auto fpair = [&](size_t n, f16** hi, f16** lo) {
    *hi = (f16*)alloc(n * 2); *lo = (f16*)alloc(n * 2);
  };
  f16 *We1h, *We1l, *We2h, *We2l, *Wih0h, *Wih0l, *Whh0h, *Whh0l, *Wih1h, *Wih1l, *Whh1h, *Whh1l;
  fpair((size_t)Hh * Dd, &We1h, &We1l);
  fpair((size_t)Hh * Hh, &We2h, &We2l);
  fpair((size_t)3 * Hh * Hh, &Wih0h, &Wih0l);
  fpair((size_t)3 * Hh * Hh, &Whh0h, &Whh0l);
  fpair((size_t)3 * Hh * Hh, &Wih1h, &Wih1l);
  fpair((size_t)3 * Hh * Hh, &Whh1h, &Whh1l);
  f16* pW1h = (f16*)alloc((size_t)Hh * Hh * 2);
  f16* pW2h = (f16*)alloc((size_t)Dd * Hh * 2);
  f16 *xhi, *xlo, *curh, *curl, *x1h, *x1l, *hn0h, *hn0l, *hn1h, *hn1l;
  fpair((size_t)Bb * Dd, &xhi, &xlo);
  fpair((size_t)Bb * Hh, &curh, &curl);
  fpair((size_t)Bb * Hh, &x1h, &x1l);
  fpair((size_t)Bb * Hh, &hn0h, &hn0l);
  fpair((size_t)Bb * Hh, &hn1h, &hn1l);
  float* hn0f = (float*)alloc((size_t)Bb * Hh * 4);
  float* hn1f = (float*)alloc((size_t)Bb * Hh * 4);
  float* gif  = (float*)alloc((size_t)Bb * 3 * Hh * 4);
  float* ghf  = (float*)alloc((size_t)Bb * 3 * Hh * 4);
  f16* outsh  = (f16*)alloc((size_t)Bb * T_STEPS * Hh * 2);
  f16* ph     = outsh;          // alias safe: outsh fully consumed by proj GEMM1 before ph written
  float* pre  = (float*)d_out;  // d_out doubles as f32 [25600,1024] proj scratch

  auto spl = [&](const float* s, f16* hi, f16* lo, int n) {
    hipLaunchKernelGGL(k_f32_split, dim3((n / 4 + 255) / 256), dim3(256), 0, stream, s, hi, lo, n);
  };
  auto conv = [&](const float* s, f16* d, int n) {
    hipLaunchKernelGGL(k_f32_to_f16, dim3((n / 4 + 255) / 256), dim3(256), 0, stream, s, d, n);
  };
  spl(x, xhi, xlo, Bb * Dd);
  spl(encW1, We1h, We1l, Hh * Dd);
  spl(encW2, We2h, We2l, Hh * Hh);
  spl(Wih0, Wih0h, Wih0l, 3 * Hh * Hh);
  spl(Whh0, Whh0h, Whh0l, 3 * Hh * Hh);
  spl(Wih1, Wih1h, Wih1l, 3 * Hh * Hh);
  spl(Whh1, Whh1h, Whh1l, 3 * Hh * Hh);
  conv(pW1, pW1h, Hh * Hh);
  conv(pW2, pW2h, Dd * Hh);
  hipLaunchKernelGGL(k_init_hn, dim3(Bb), dim3(256), 0, stream, hnb, hn0f, hn1f, hn0h, hn0l, hn1h, hn1l);

  // ---------- encoder (split precision) ----------
  hipLaunchKernelGGL(k_gemm3, dim3(Bb / BM, Hh / BN), dim3(256), 0, stream,
                     xhi, xlo, We1h, We1l, gif, encb1, Hh);
  hipLaunchKernelGGL(k_ln_relu, dim3(Bb), dim3(256), 0, stream, gif, ln1g, ln1b, x1h, x1l);
  hipLaunchKernelGGL(k_gemm3, dim3(Bb / BM, Hh / BN), dim3(256), 0, stream,
                     x1h, x1l, We2h, We2l, gif, encb2, Hh);
  hipLaunchKernelGGL(k_ln_relu, dim3(Bb), dim3(256), 0, stream, gif, ln2g, ln2b, curh, curl);

  // ---------- GRU: 100 steps x 2 layers, pipelined fused-3 split GEMMs ----------
  for (int t = 0; t < T_STEPS; ++t) {
    hipLaunchKernelGGL(k_gru_gemm, dim3(256), dim3(256), 0, stream,
                       curh, curl, Wih0h, Wih0l, gif, hn0h, hn0l, Whh0h, Whh0l, ghf);
    hipLaunchKernelGGL(k_gru_gate, dim3(Bb), dim3(256), 0, stream,
                       gif, ghf, hn0f, hn0h, hn0l, x1h, x1l, bih0, bhh0, hng, hnb,
                       (f16*)nullptr, (long)0);
    hipLaunchKernelGGL(k_gru_gemm, dim3(256), dim3(256), 0, stream,
                       x1h, x1l, Wih1h, Wih1l, gif, hn1h, hn1l, Whh1h, Whh1l, ghf);
    hipLaunchKernelGGL(k_gru_gate, dim3(Bb), dim3(256), 0, stream,
                       gif, ghf, hn1f, hn1h, hn1l, curh, curl, bih1, bhh1, hng, hnb,
                       outsh + (size_t)t * Hh, (long)T_STEPS * Hh);
  }

  // ---------- projection (single f16, 128x128 tiles) ----------
  hipLaunchKernelGGL(k_gemm_big, dim3(Bb * T_STEPS / 128, Hh / 128), dim3(256), 0, stream,
                     outsh, pW1h, pre, pb1, Hh);
  hipLaunchKernelGGL(k_ln_relu, dim3(Bb * T_STEPS), dim3(256), 0, stream, pre, plng, plnb,
                     ph, (f16*)nullptr);
  hipLaunchKernelGGL(k_gemm_big, dim3(Bb * T_STEPS / 128, Dd / 128), dim3(256), 0, stream,
                     ph, pW2h, (float*)d_out, pb2, Dd);
}